// Round 9
// baseline (308.152 us; speedup 1.0000x reference)
//
#include <hip/hip_runtime.h>
#include <hip/hip_bf16.h>
#include <math.h>

#define BB 8
#define LL 2048
#define DMODEL 512
#define DINNER 1024
#define DSSM 512
#define NST 16
#define DTR 32
#define NXD 640           // xdbl2 row stride (512 dt + 16 k + 16 q + 96 pad)
#define CCH 64            // scan chunks
#define LC (LL / CCH)     // 32 steps per chunk
#define BDN (BB * DSSM * NST)  // 65536 scan lanes
#define CLW 8             // conv l-steps per thread

typedef short short8 __attribute__((ext_vector_type(8)));
typedef float f32x4 __attribute__((ext_vector_type(4)));

// ---- bf16 helpers (RNE, bit-level) ----------------------------------------
__device__ __forceinline__ unsigned short f2bf(float f) {
  unsigned u = __float_as_uint(f);
  u += 0x7FFFu + ((u >> 16) & 1u);
  return (unsigned short)(u >> 16);
}
__device__ __forceinline__ float bf2f(unsigned short s) {
  return __uint_as_float(((unsigned)s) << 16);
}

__device__ __forceinline__ void gload16(const void* g, void* l) {
  __builtin_amdgcn_global_load_lds(
      (const __attribute__((address_space(1))) void*)g,
      (__attribute__((address_space(3))) void*)l, 16, 0, 0);
}

// ---------------------------------------------------------------------------
// bf16 MFMA GEMM: C[M,N] = A[M,K] * W[N,K]^T  (bf16 in, fp32 acc).
// 128x128 tile, BK=64, 256 thr (4 waves, 2x2 of 64x64). LDS rows = 128B
// (64 k-elems), 16B-granule-XOR-swizzled (source-side + read-side).
// OUTBF: write bf16 else fp32.
// ---------------------------------------------------------------------------
template<bool OUTBF>
__global__ __launch_bounds__(256) void gemm_bf16(
    const unsigned short* __restrict__ Ab,
    const unsigned short* __restrict__ Wb,
    void* __restrict__ Cout, int K, int NBN) {
  __shared__ unsigned short tA[128 * 64];
  __shared__ unsigned short tW[128 * 64];
  const int tid = threadIdx.x;
  const int ln = tid & 63;
  const int wv = tid >> 6;
  const int wr = wv >> 1, wc = wv & 1;
  const int lr = ln & 15, kc = ln >> 4;

  // XCD-chunked bijective swizzle (nwg % 8 == 0), M-major order.
  const int nwg = gridDim.x;
  const int q = nwg >> 3;
  const int bid = blockIdx.x;
  const int wg = (bid & 7) * q + (bid >> 3);
  const int mblk = wg / NBN, nblk = wg % NBN;
  const size_t m0 = (size_t)mblk * 128, n0 = (size_t)nblk * 128;

  f32x4 acc[4][4];
#pragma unroll
  for (int m = 0; m < 4; ++m)
#pragma unroll
    for (int n = 0; n < 4; ++n)
#pragma unroll
      for (int j = 0; j < 4; ++j) acc[m][n][j] = 0.f;

  const int wbase = (tid & 0xC0) << 4;  // wave-uniform byte base

  for (int k0 = 0; k0 < K; k0 += 64) {
#pragma unroll
    for (int it = 0; it < 4; ++it) {
      const int gi = it * 256 + tid;
      const int r = gi >> 3, s = gi & 7, g = s ^ (r & 7);
      const size_t off = (m0 + r) * (size_t)K + (size_t)(k0 + g * 8);
      gload16(Ab + off, (char*)tA + it * 4096 + wbase);
    }
#pragma unroll
    for (int it = 0; it < 4; ++it) {
      const int gi = it * 256 + tid;
      const int r = gi >> 3, s = gi & 7, g = s ^ (r & 7);
      const size_t off = (n0 + r) * (size_t)K + (size_t)(k0 + g * 8);
      gload16(Wb + off, (char*)tW + it * 4096 + wbase);
    }
    __syncthreads();

    short8 alo[4], ahi[4], wlo[4], whi[4];
#pragma unroll
    for (int m = 0; m < 4; ++m) {
      const int ra = wr * 64 + m * 16 + lr;
      const int sl = kc ^ (ra & 7);
      const char* base = (const char*)tA + ra * 128;
      alo[m] = *(const short8*)(base + sl * 16);
      ahi[m] = *(const short8*)(base + (sl ^ 4) * 16);
    }
#pragma unroll
    for (int n = 0; n < 4; ++n) {
      const int rb = wc * 64 + n * 16 + lr;
      const int sl = kc ^ (rb & 7);
      const char* base = (const char*)tW + rb * 128;
      wlo[n] = *(const short8*)(base + sl * 16);
      whi[n] = *(const short8*)(base + (sl ^ 4) * 16);
    }
#pragma unroll
    for (int m = 0; m < 4; ++m)
#pragma unroll
      for (int n = 0; n < 4; ++n) {
        acc[m][n] = __builtin_amdgcn_mfma_f32_16x16x32_bf16(alo[m], wlo[n], acc[m][n], 0, 0, 0);
        acc[m][n] = __builtin_amdgcn_mfma_f32_16x16x32_bf16(ahi[m], whi[n], acc[m][n], 0, 0, 0);
      }
    __syncthreads();
  }

  // C/D layout: col = lane&15, row = (lane>>4)*4 + reg
  const int ldc = NBN * 128;
#pragma unroll
  for (int m = 0; m < 4; ++m) {
    const size_t row0 = m0 + wr * 64 + m * 16 + kc * 4;
#pragma unroll
    for (int n = 0; n < 4; ++n) {
      const size_t col = n0 + wc * 64 + n * 16 + lr;
#pragma unroll
      for (int j = 0; j < 4; ++j) {
        if (OUTBF)
          ((unsigned short*)Cout)[(row0 + j) * (size_t)ldc + col] = f2bf(acc[m][n][j]);
        else
          ((float*)Cout)[(row0 + j) * (size_t)ldc + col] = acc[m][n][j];
      }
    }
  }
}

// ---------------------------------------------------------------------------
// Fused prep: fp32 -> bf16 for hidden / W_in / W_out (segmented grid).
// ---------------------------------------------------------------------------
__global__ __launch_bounds__(256) void prep_kernel(
    const float* __restrict__ hidden, const float* __restrict__ W_in,
    const float* __restrict__ W_out,
    unsigned short* __restrict__ hidB, unsigned short* __restrict__ WinB,
    unsigned short* __restrict__ WoutB, int nHid4, int nW4) {
  const int bx = blockIdx.x;
  const float* in;
  unsigned short* o;
  int i, str, n4;
  if (bx < 2048) {
    in = hidden; o = hidB; i = bx * 256 + threadIdx.x; str = 2048 * 256; n4 = nHid4;
  } else if (bx < 2176) {
    in = W_in; o = WinB; i = (bx - 2048) * 256 + threadIdx.x; str = 128 * 256; n4 = nW4;
  } else {
    in = W_out; o = WoutB; i = (bx - 2176) * 256 + threadIdx.x; str = 128 * 256; n4 = nW4;
  }
  for (; i < n4; i += str) {
    const float4 v = ((const float4*)in)[i];
    ushort4 h;
    h.x = f2bf(v.x); h.y = f2bf(v.y); h.z = f2bf(v.z); h.w = f2bf(v.w);
    ((ushort4*)o)[i] = h;
  }
}

// ---------------------------------------------------------------------------
// Wcat[640][512] bf16: rows 0..511 = W_dt @ W_xproj[:32]  (dt fusion),
// rows 512..543 = W_xproj[32:64] (k,q), rows 544..639 = 0 (tile pad).
// ---------------------------------------------------------------------------
__global__ __launch_bounds__(256) void weff_kernel(
    const float* __restrict__ W_dt, const float* __restrict__ W_xproj,
    unsigned short* __restrict__ WcatB) {
  const int c = blockIdx.x * 256 + threadIdx.x;   // 0..511
  const int r0 = blockIdx.y;                      // 0..639
  float v;
  if (r0 < 512) {
    float acc = 0.f;
#pragma unroll
    for (int r = 0; r < 32; r++)
      acc = fmaf(W_dt[r0 * 32 + r], W_xproj[r * 512 + c], acc);
    v = acc;
  } else if (r0 < 544) {
    v = W_xproj[(r0 - 480) * 512 + c];   // row 32 + (r0-512)
  } else {
    v = 0.f;
  }
  WcatB[(size_t)r0 * 512 + c] = f2bf(v);
}

// ---------------------------------------------------------------------------
// Depthwise conv + bias + SiLU, register-walk CLW l-steps per thread.
// xz bf16 in. x-half -> xcB (bf16); z-half -> yB (bf16).
// ---------------------------------------------------------------------------
__global__ __launch_bounds__(256) void conv_silu_kernel(
    const unsigned short* __restrict__ xzB,
    const float* __restrict__ cxw, const float* __restrict__ cxb,
    const float* __restrict__ czw, const float* __restrict__ czb,
    unsigned short* __restrict__ xcB, unsigned short* __restrict__ yB) {
  const int c = blockIdx.x * 256 + threadIdx.x;  // 0..1023
  const int l0 = blockIdx.y * CLW;
  const int b = blockIdx.z;
  float w0, w1, w2, w3, bias;
  if (c < DSSM) {
    w0 = cxw[c * 4 + 0]; w1 = cxw[c * 4 + 1]; w2 = cxw[c * 4 + 2]; w3 = cxw[c * 4 + 3];
    bias = cxb[c];
  } else {
    const int cz = c - DSSM;
    w0 = czw[cz * 4 + 0]; w1 = czw[cz * 4 + 1]; w2 = czw[cz * 4 + 2]; w3 = czw[cz * 4 + 3];
    bias = czb[cz];
  }
  const unsigned short* base = xzB + ((size_t)b * LL + l0) * DINNER + c;
  float v[CLW + 3];
  v[0] = (l0 > 0) ? bf2f(base[-(int)DINNER]) : 0.f;
#pragma unroll
  for (int i = 0; i <= CLW + 1; i++) {
    const int l = l0 + i;
    v[i + 1] = (l < LL) ? bf2f(base[(size_t)i * DINNER]) : 0.f;
  }
#pragma unroll
  for (int j = 0; j < CLW; j++) {
    float a = bias;
    a = fmaf(v[j + 0], w0, a);
    a = fmaf(v[j + 1], w1, a);
    a = fmaf(v[j + 2], w2, a);
    a = fmaf(v[j + 3], w3, a);
    const float y = a / (1.f + expf(-a));  // SiLU
    const size_t bl = (size_t)b * LL + l0 + j;
    if (c < DSSM)
      xcB[bl * DSSM + c] = f2bf(y);
    else
      yB[bl * DINNER + c] = f2bf(y);
  }
}

// ---------------------------------------------------------------------------
// Chunked scan with INLINE eps: per step load dt,k (bf16), compute
// delta = softplus(dt + b_dt), k2 = sum k^2, e = delta/(1+delta*k2).
// 16 n-states in registers per (b,d) thread.
// ---------------------------------------------------------------------------
__device__ __forceinline__ void load_bf16x16(const unsigned short* p, float* o) {
  short8 lo = *(const short8*)p;
  short8 hi = *(const short8*)(p + 8);
#pragma unroll
  for (int n = 0; n < 8; n++) o[n] = bf2f((unsigned short)lo[n]);
#pragma unroll
  for (int n = 0; n < 8; n++) o[8 + n] = bf2f((unsigned short)hi[n]);
}

__global__ __launch_bounds__(256) void scan_passA(
    const unsigned short* __restrict__ xdbl2B,
    const unsigned short* __restrict__ xcB, const float* __restrict__ b_dt,
    float* __restrict__ Ach, float* __restrict__ Bch) {
  const int d = blockIdx.x * 256 + threadIdx.x;
  const int b = blockIdx.y, ch = blockIdx.z;
  const size_t bl0 = (size_t)b * LL + (size_t)ch * LC;
  const unsigned short* dtp = xdbl2B + bl0 * NXD + d;
  const unsigned short* up = xcB + bl0 * DSSM + d;
  const unsigned short* kqp = xdbl2B + bl0 * NXD + 512;
  const float bdt = b_dt[d];
  float A[16], S[16];
#pragma unroll
  for (int n = 0; n < 16; n++) { A[n] = 1.f; S[n] = 0.f; }
#pragma unroll 2
  for (int j = 0; j < LC; j++) {
    float kv[16];
    load_bf16x16(kqp + (size_t)j * NXD, kv);   // uniform address
    float k2 = 0.f;
#pragma unroll
    for (int n = 0; n < 16; n++) k2 = fmaf(kv[n], kv[n], k2);
    const float dt = bf2f(dtp[(size_t)j * NXD]) + bdt;
    const float delta = (dt > 20.f) ? dt : log1pf(expf(dt));
    const float e = delta / (1.f + delta * k2);
    const float u = bf2f(up[(size_t)j * DSSM]);
#pragma unroll
    for (int n = 0; n < 16; n++) {
      const float t0 = e * kv[n];
      const float a = fmaf(-t0, kv[n], 1.f);
      A[n] *= a;
      S[n] = fmaf(S[n], a, t0 * u);
    }
  }
  const size_t base = (size_t)ch * BDN + (((size_t)b * DSSM + d) << 4);
#pragma unroll
  for (int n4 = 0; n4 < 4; n4++) {
    ((float4*)(Ach + base))[n4] =
        make_float4(A[4 * n4], A[4 * n4 + 1], A[4 * n4 + 2], A[4 * n4 + 3]);
    ((float4*)(Bch + base))[n4] =
        make_float4(S[4 * n4], S[4 * n4 + 1], S[4 * n4 + 2], S[4 * n4 + 3]);
  }
}

__global__ __launch_bounds__(256) void scan_passB(
    const float* __restrict__ Ach, const float* __restrict__ Bch,
    float* __restrict__ S0) {
  const size_t i = (size_t)blockIdx.x * 256 + threadIdx.x;  // 65536 lanes
  float S = 0.f;
  for (int ch = 0; ch < CCH; ch++) {
    const size_t off = (size_t)ch * BDN + i;
    const float a = Ach[off];
    const float bv = Bch[off];
    S0[off] = S;           // exclusive: carry INTO chunk ch
    S = fmaf(S, a, bv);
  }
}

__global__ __launch_bounds__(256) void scan_passC(
    const unsigned short* __restrict__ xdbl2B,
    const unsigned short* __restrict__ xcB, const float* __restrict__ b_dt,
    const float* __restrict__ D_skip, const float* __restrict__ S0,
    unsigned short* __restrict__ yB) {
  const int d = blockIdx.x * 256 + threadIdx.x;
  const int b = blockIdx.y, ch = blockIdx.z;
  const size_t bl0 = (size_t)b * LL + (size_t)ch * LC;
  const unsigned short* dtp = xdbl2B + bl0 * NXD + d;
  const unsigned short* up = xcB + bl0 * DSSM + d;
  const unsigned short* kqp = xdbl2B + bl0 * NXD + 512;
  unsigned short* yp = yB + bl0 * DINNER + d;
  const float bdt = b_dt[d];
  const float Dv = D_skip[d];
  const size_t base = (size_t)ch * BDN + (((size_t)b * DSSM + d) << 4);
  float S[16];
#pragma unroll
  for (int n4 = 0; n4 < 4; n4++) {
    const float4 v = ((const float4*)(S0 + base))[n4];
    S[4 * n4 + 0] = v.x; S[4 * n4 + 1] = v.y;
    S[4 * n4 + 2] = v.z; S[4 * n4 + 3] = v.w;
  }
#pragma unroll 2
  for (int j = 0; j < LC; j++) {
    float kv[16], qv[16];
    load_bf16x16(kqp + (size_t)j * NXD, kv);       // uniform
    load_bf16x16(kqp + (size_t)j * NXD + 16, qv);  // uniform
    float k2 = 0.f;
#pragma unroll
    for (int n = 0; n < 16; n++) k2 = fmaf(kv[n], kv[n], k2);
    const float dt = bf2f(dtp[(size_t)j * NXD]) + bdt;
    const float delta = (dt > 20.f) ? dt : log1pf(expf(dt));
    const float e = delta / (1.f + delta * k2);
    const float u = bf2f(up[(size_t)j * DSSM]);
    float y0 = 0.f, y1 = 0.f, y2 = 0.f, y3 = 0.f;
#pragma unroll
    for (int n = 0; n < 16; n += 4) {
      const float t00 = e * kv[n + 0], t01 = e * kv[n + 1];
      const float t02 = e * kv[n + 2], t03 = e * kv[n + 3];
      S[n + 0] = fmaf(S[n + 0], fmaf(-t00, kv[n + 0], 1.f), t00 * u);
      S[n + 1] = fmaf(S[n + 1], fmaf(-t01, kv[n + 1], 1.f), t01 * u);
      S[n + 2] = fmaf(S[n + 2], fmaf(-t02, kv[n + 2], 1.f), t02 * u);
      S[n + 3] = fmaf(S[n + 3], fmaf(-t03, kv[n + 3], 1.f), t03 * u);
      y0 = fmaf(S[n + 0], qv[n + 0], y0);
      y1 = fmaf(S[n + 1], qv[n + 1], y1);
      y2 = fmaf(S[n + 2], qv[n + 2], y2);
      y3 = fmaf(S[n + 3], qv[n + 3], y3);
    }
    const float yv = fmaf(Dv, u, (y0 + y1) + (y2 + y3));
    yp[(size_t)j * DINNER] = f2bf(yv);
  }
}

// ---------------------------------------------------------------------------
extern "C" void kernel_launch(void* const* d_in, const int* in_sizes, int n_in,
                              void* d_out, int out_size, void* d_ws, size_t ws_size,
                              hipStream_t stream) {
  const float* hidden  = (const float*)d_in[0];
  const float* W_in    = (const float*)d_in[1];
  const float* cxw     = (const float*)d_in[2];
  const float* cxb     = (const float*)d_in[3];
  const float* czw     = (const float*)d_in[4];
  const float* czb     = (const float*)d_in[5];
  const float* W_xproj = (const float*)d_in[6];
  const float* W_dt    = (const float*)d_in[7];
  const float* b_dt    = (const float*)d_in[8];
  const float* D_skip  = (const float*)d_in[9];
  const float* W_out   = (const float*)d_in[10];
  float* out = (float*)d_out;

  const size_t ML  = (size_t)BB * LL;      // 16384
  const size_t MK5 = ML * DSSM;            // 8.4M
  const size_t MN  = ML * DINNER;          // 16.8M
  const size_t WIN = (size_t)DINNER * DMODEL;
  const size_t WOU = (size_t)DMODEL * DINNER;
  const size_t WCT = (size_t)NXD * DMODEL; // 640*512
  const size_t CB  = (size_t)CCH * BDN;    // 4.19M floats

  // layout: hidB+xzB at the end so Ach/Bch/S0 (3*CB floats) alias them exactly.
  unsigned short* WinB   = (unsigned short*)d_ws;       // WIN
  unsigned short* WoutB  = WinB + WIN;                  // WOU
  unsigned short* WcatB  = WoutB + WOU;                 // WCT
  unsigned short* xcB    = WcatB + WCT;                 // MK5
  unsigned short* yB     = xcB + MK5;                   // MN
  unsigned short* xdbl2B = yB + MN;                     // ML*NXD
  unsigned short* hidB   = xdbl2B + ML * NXD;           // MK5
  unsigned short* xzB    = hidB + MK5;                  // MN
  float* Ach = (float*)hidB;     // 3*CB floats == hidB+xzB bytes exactly
  float* Bch = Ach + CB;
  float* S0  = Bch + CB;

  // 0) fp32 -> bf16 planes (fused) ; fused weight build
  prep_kernel<<<2304, 256, 0, stream>>>(hidden, W_in, W_out, hidB, WinB, WoutB,
                                        (int)(MK5 / 4), (int)(WIN / 4));
  weff_kernel<<<dim3(2, NXD), 256, 0, stream>>>(W_dt, W_xproj, WcatB);

  // 1) xz = hidden @ W_in^T   (bf16 MFMA; M=16384, N=1024, K=512; bf16 out)
  gemm_bf16<true><<<(16384 / 128) * (1024 / 128), 256, 0, stream>>>(
      hidB, WinB, xzB, DMODEL, DINNER / 128);

  // 2) depthwise conv + SiLU  (bf16 in; xcB + yB z-half bf16)
  conv_silu_kernel<<<dim3(DINNER / 256, LL / CLW, BB), 256, 0, stream>>>(
      xzB, cxw, cxb, czw, czb, xcB, yB);

  // 3) xdbl2 = xc @ Wcat^T  (bf16 MFMA; M=16384, N=640, K=512; bf16 out)
  //    cols 0..511 = dt, 512..527 = k, 528..543 = q
  gemm_bf16<true><<<(16384 / 128) * (NXD / 128), 256, 0, stream>>>(
      xcB, WcatB, xdbl2B, DMODEL, NXD / 128);

  // 4+5) chunked scan with inline eps -> y into yB channels 0..511
  scan_passA<<<dim3(2, BB, CCH), 256, 0, stream>>>(xdbl2B, xcB, b_dt, Ach, Bch);
  scan_passB<<<dim3(BDN / 256), 256, 0, stream>>>(Ach, Bch, S0);
  scan_passC<<<dim3(2, BB, CCH), 256, 0, stream>>>(
      xdbl2B, xcB, b_dt, D_skip, S0, yB);

  // 6) out = ycat @ W_out^T  (bf16 MFMA; M=16384, N=512, K=1024; fp32 out)
  gemm_bf16<false><<<(16384 / 128) * (512 / 128), 256, 0, stream>>>(
      yB, WoutB, out, DINNER, DMODEL / 128);
}

// Round 11
// 286.008 us; speedup vs baseline: 1.0774x; 1.0774x over previous
//
#include <hip/hip_runtime.h>
#include <hip/hip_bf16.h>
#include <math.h>

#define BB 8
#define LL 2048
#define DMODEL 512
#define DINNER 1024
#define DSSM 512
#define NST 16
#define DTR 32
#define NXD 640           // xdbl2 row stride (512 dt + 16 k + 16 q + 96 pad)
#define CCH 64            // scan chunks
#define LC (LL / CCH)     // 32 steps per chunk
#define BDN (BB * DSSM * NST)  // 65536 scan lanes
#define CLW 8             // conv l-steps per thread

typedef short short8 __attribute__((ext_vector_type(8)));
typedef float f32x4 __attribute__((ext_vector_type(4)));

// ---- bf16 helpers (RNE, bit-level) ----------------------------------------
__device__ __forceinline__ unsigned short f2bf(float f) {
  unsigned u = __float_as_uint(f);
  u += 0x7FFFu + ((u >> 16) & 1u);
  return (unsigned short)(u >> 16);
}
__device__ __forceinline__ float bf2f(unsigned short s) {
  return __uint_as_float(((unsigned)s) << 16);
}

__device__ __forceinline__ void gload16(const void* g, void* l) {
  __builtin_amdgcn_global_load_lds(
      (const __attribute__((address_space(1))) void*)g,
      (__attribute__((address_space(3))) void*)l, 16, 0, 0);
}

// ---------------------------------------------------------------------------
// bf16 MFMA GEMM: C[M,N] = A[M,K] * W[N,K]^T  (bf16 in, fp32 acc).
// 128x128 tile, BK=64, 256 thr (4 waves, 2x2 of 64x64). LDS rows = 128B
// (64 k-elems), 16B-granule-XOR-swizzled (source-side + read-side).
// OUTBF: write bf16 else fp32.
// ---------------------------------------------------------------------------
template<bool OUTBF>
__global__ __launch_bounds__(256) void gemm_bf16(
    const unsigned short* __restrict__ Ab,
    const unsigned short* __restrict__ Wb,
    void* __restrict__ Cout, int K, int NBN) {
  __shared__ unsigned short tA[128 * 64];
  __shared__ unsigned short tW[128 * 64];
  const int tid = threadIdx.x;
  const int ln = tid & 63;
  const int wv = tid >> 6;
  const int wr = wv >> 1, wc = wv & 1;
  const int lr = ln & 15, kc = ln >> 4;

  // XCD-chunked bijective swizzle (nwg % 8 == 0), M-major order.
  const int nwg = gridDim.x;
  const int q = nwg >> 3;
  const int bid = blockIdx.x;
  const int wg = (bid & 7) * q + (bid >> 3);
  const int mblk = wg / NBN, nblk = wg % NBN;
  const size_t m0 = (size_t)mblk * 128, n0 = (size_t)nblk * 128;

  f32x4 acc[4][4];
#pragma unroll
  for (int m = 0; m < 4; ++m)
#pragma unroll
    for (int n = 0; n < 4; ++n)
#pragma unroll
      for (int j = 0; j < 4; ++j) acc[m][n][j] = 0.f;

  const int wbase = (tid & 0xC0) << 4;  // wave-uniform byte base

  for (int k0 = 0; k0 < K; k0 += 64) {
#pragma unroll
    for (int it = 0; it < 4; ++it) {
      const int gi = it * 256 + tid;
      const int r = gi >> 3, s = gi & 7, g = s ^ (r & 7);
      const size_t off = (m0 + r) * (size_t)K + (size_t)(k0 + g * 8);
      gload16(Ab + off, (char*)tA + it * 4096 + wbase);
    }
#pragma unroll
    for (int it = 0; it < 4; ++it) {
      const int gi = it * 256 + tid;
      const int r = gi >> 3, s = gi & 7, g = s ^ (r & 7);
      const size_t off = (n0 + r) * (size_t)K + (size_t)(k0 + g * 8);
      gload16(Wb + off, (char*)tW + it * 4096 + wbase);
    }
    __syncthreads();

    short8 alo[4], ahi[4], wlo[4], whi[4];
#pragma unroll
    for (int m = 0; m < 4; ++m) {
      const int ra = wr * 64 + m * 16 + lr;
      const int sl = kc ^ (ra & 7);
      const char* base = (const char*)tA + ra * 128;
      alo[m] = *(const short8*)(base + sl * 16);
      ahi[m] = *(const short8*)(base + (sl ^ 4) * 16);
    }
#pragma unroll
    for (int n = 0; n < 4; ++n) {
      const int rb = wc * 64 + n * 16 + lr;
      const int sl = kc ^ (rb & 7);
      const char* base = (const char*)tW + rb * 128;
      wlo[n] = *(const short8*)(base + sl * 16);
      whi[n] = *(const short8*)(base + (sl ^ 4) * 16);
    }
#pragma unroll
    for (int m = 0; m < 4; ++m)
#pragma unroll
      for (int n = 0; n < 4; ++n) {
        acc[m][n] = __builtin_amdgcn_mfma_f32_16x16x32_bf16(alo[m], wlo[n], acc[m][n], 0, 0, 0);
        acc[m][n] = __builtin_amdgcn_mfma_f32_16x16x32_bf16(ahi[m], whi[n], acc[m][n], 0, 0, 0);
      }
    __syncthreads();
  }

  // C/D layout: col = lane&15, row = (lane>>4)*4 + reg
  const int ldc = NBN * 128;
#pragma unroll
  for (int m = 0; m < 4; ++m) {
    const size_t row0 = m0 + wr * 64 + m * 16 + kc * 4;
#pragma unroll
    for (int n = 0; n < 4; ++n) {
      const size_t col = n0 + wc * 64 + n * 16 + lr;
#pragma unroll
      for (int j = 0; j < 4; ++j) {
        if (OUTBF)
          ((unsigned short*)Cout)[(row0 + j) * (size_t)ldc + col] = f2bf(acc[m][n][j]);
        else
          ((float*)Cout)[(row0 + j) * (size_t)ldc + col] = acc[m][n][j];
      }
    }
  }
}

// ---------------------------------------------------------------------------
// Fused prep: fp32 -> bf16 for hidden / W_in / W_out (segmented grid).
// ---------------------------------------------------------------------------
__global__ __launch_bounds__(256) void prep_kernel(
    const float* __restrict__ hidden, const float* __restrict__ W_in,
    const float* __restrict__ W_out,
    unsigned short* __restrict__ hidB, unsigned short* __restrict__ WinB,
    unsigned short* __restrict__ WoutB, int nHid4, int nW4) {
  const int bx = blockIdx.x;
  const float* in;
  unsigned short* o;
  int i, str, n4;
  if (bx < 2048) {
    in = hidden; o = hidB; i = bx * 256 + threadIdx.x; str = 2048 * 256; n4 = nHid4;
  } else if (bx < 2176) {
    in = W_in; o = WinB; i = (bx - 2048) * 256 + threadIdx.x; str = 128 * 256; n4 = nW4;
  } else {
    in = W_out; o = WoutB; i = (bx - 2176) * 256 + threadIdx.x; str = 128 * 256; n4 = nW4;
  }
  for (; i < n4; i += str) {
    const float4 v = ((const float4*)in)[i];
    ushort4 h;
    h.x = f2bf(v.x); h.y = f2bf(v.y); h.z = f2bf(v.z); h.w = f2bf(v.w);
    ((ushort4*)o)[i] = h;
  }
}

// ---------------------------------------------------------------------------
// Wcat[640][512] bf16: rows 0..511 = W_dt @ W_xproj[:32]  (dt fusion),
// rows 512..543 = W_xproj[32:64] (k,q), rows 544..639 = 0 (tile pad).
// ---------------------------------------------------------------------------
__global__ __launch_bounds__(256) void weff_kernel(
    const float* __restrict__ W_dt, const float* __restrict__ W_xproj,
    unsigned short* __restrict__ WcatB) {
  const int c = blockIdx.x * 256 + threadIdx.x;   // 0..511
  const int r0 = blockIdx.y;                      // 0..639
  float v;
  if (r0 < 512) {
    float acc = 0.f;
#pragma unroll
    for (int r = 0; r < 32; r++)
      acc = fmaf(W_dt[r0 * 32 + r], W_xproj[r * 512 + c], acc);
    v = acc;
  } else if (r0 < 544) {
    v = W_xproj[(r0 - 480) * 512 + c];   // row 32 + (r0-512)
  } else {
    v = 0.f;
  }
  WcatB[(size_t)r0 * 512 + c] = f2bf(v);
}

// ---------------------------------------------------------------------------
// Depthwise conv + bias + SiLU, register-walk CLW l-steps per thread.
// xz bf16 in. x-half -> xcB (bf16); z-half -> yB (bf16).
// ---------------------------------------------------------------------------
__global__ __launch_bounds__(256) void conv_silu_kernel(
    const unsigned short* __restrict__ xzB,
    const float* __restrict__ cxw, const float* __restrict__ cxb,
    const float* __restrict__ czw, const float* __restrict__ czb,
    unsigned short* __restrict__ xcB, unsigned short* __restrict__ yB) {
  const int c = blockIdx.x * 256 + threadIdx.x;  // 0..1023
  const int l0 = blockIdx.y * CLW;
  const int b = blockIdx.z;
  float w0, w1, w2, w3, bias;
  if (c < DSSM) {
    w0 = cxw[c * 4 + 0]; w1 = cxw[c * 4 + 1]; w2 = cxw[c * 4 + 2]; w3 = cxw[c * 4 + 3];
    bias = cxb[c];
  } else {
    const int cz = c - DSSM;
    w0 = czw[cz * 4 + 0]; w1 = czw[cz * 4 + 1]; w2 = czw[cz * 4 + 2]; w3 = czw[cz * 4 + 3];
    bias = czb[cz];
  }
  const unsigned short* base = xzB + ((size_t)b * LL + l0) * DINNER + c;
  float v[CLW + 3];
  v[0] = (l0 > 0) ? bf2f(base[-(int)DINNER]) : 0.f;
#pragma unroll
  for (int i = 0; i <= CLW + 1; i++) {
    const int l = l0 + i;
    v[i + 1] = (l < LL) ? bf2f(base[(size_t)i * DINNER]) : 0.f;
  }
#pragma unroll
  for (int j = 0; j < CLW; j++) {
    float a = bias;
    a = fmaf(v[j + 0], w0, a);
    a = fmaf(v[j + 1], w1, a);
    a = fmaf(v[j + 2], w2, a);
    a = fmaf(v[j + 3], w3, a);
    const float y = a / (1.f + expf(-a));  // SiLU
    const size_t bl = (size_t)b * LL + l0 + j;
    if (c < DSSM)
      xcB[bl * DSSM + c] = f2bf(y);
    else
      yB[bl * DINNER + c] = f2bf(y);
  }
}

// ---------------------------------------------------------------------------
__device__ __forceinline__ void load_bf16x16(const unsigned short* p, float* o) {
  short8 lo = *(const short8*)p;
  short8 hi = *(const short8*)(p + 8);
#pragma unroll
  for (int n = 0; n < 8; n++) o[n] = bf2f((unsigned short)lo[n]);
#pragma unroll
  for (int n = 0; n < 8; n++) o[8 + n] = bf2f((unsigned short)hi[n]);
}

// ---------------------------------------------------------------------------
// dteps2: one block per (b,l) row. delta = softplus(dt + b_dt);
// k2 = sum k^2 (uniform); eps = delta/(1+delta*k2) -> bf16.
// ---------------------------------------------------------------------------
__global__ __launch_bounds__(256) void dteps2_kernel(
    const unsigned short* __restrict__ xdbl2B, const float* __restrict__ b_dt,
    unsigned short* __restrict__ epsB) {
  const size_t row = blockIdx.x;
  const unsigned short* rp = xdbl2B + row * NXD;
  float kv[16];
  load_bf16x16(rp + 512, kv);
  float k2 = 0.f;
#pragma unroll
  for (int n = 0; n < 16; n++) k2 = fmaf(kv[n], kv[n], k2);
#pragma unroll
  for (int rep = 0; rep < 2; rep++) {
    const int d = rep * 256 + threadIdx.x;
    const float dt = bf2f(rp[d]) + b_dt[d];
    const float delta = (dt > 20.f) ? dt : log1pf(expf(dt));
    epsB[row * DSSM + d] = f2bf(delta / (1.f + delta * k2));
  }
}

// ---------------------------------------------------------------------------
// Chunked scan, thread-per-(b,d): 16 n-states in registers. All bf16 inputs.
// ---------------------------------------------------------------------------
__global__ __launch_bounds__(256) void scan_passA(
    const unsigned short* __restrict__ epsB,
    const unsigned short* __restrict__ xcB,
    const unsigned short* __restrict__ xdbl2B,
    float* __restrict__ Ach, float* __restrict__ Bch) {
  const int d = blockIdx.x * 256 + threadIdx.x;
  const int b = blockIdx.y, ch = blockIdx.z;
  const size_t bl0 = (size_t)b * LL + (size_t)ch * LC;
  const unsigned short* ep = epsB + bl0 * DSSM + d;
  const unsigned short* up = xcB + bl0 * DSSM + d;
  const unsigned short* kqp = xdbl2B + bl0 * NXD + 512;
  float A[16], S[16];
#pragma unroll
  for (int n = 0; n < 16; n++) { A[n] = 1.f; S[n] = 0.f; }
#pragma unroll 2
  for (int j = 0; j < LC; j++) {
    float kv[16];
    load_bf16x16(kqp + (size_t)j * NXD, kv);   // uniform address
    const float e = bf2f(ep[(size_t)j * DSSM]);
    const float u = bf2f(up[(size_t)j * DSSM]);
#pragma unroll
    for (int n = 0; n < 16; n++) {
      const float t0 = e * kv[n];
      const float a = fmaf(-t0, kv[n], 1.f);
      A[n] *= a;
      S[n] = fmaf(S[n], a, t0 * u);
    }
  }
  const size_t base = (size_t)ch * BDN + (((size_t)b * DSSM + d) << 4);
#pragma unroll
  for (int n4 = 0; n4 < 4; n4++) {
    ((float4*)(Ach + base))[n4] =
        make_float4(A[4 * n4], A[4 * n4 + 1], A[4 * n4 + 2], A[4 * n4 + 3]);
    ((float4*)(Bch + base))[n4] =
        make_float4(S[4 * n4], S[4 * n4 + 1], S[4 * n4 + 2], S[4 * n4 + 3]);
  }
}

__global__ __launch_bounds__(256) void scan_passB(
    const float* __restrict__ Ach, const float* __restrict__ Bch,
    float* __restrict__ S0) {
  const size_t i = (size_t)blockIdx.x * 256 + threadIdx.x;  // 65536 lanes
  float S = 0.f;
  for (int ch = 0; ch < CCH; ch++) {
    const size_t off = (size_t)ch * BDN + i;
    const float a = Ach[off];
    const float bv = Bch[off];
    S0[off] = S;           // exclusive: carry INTO chunk ch
    S = fmaf(S, a, bv);
  }
}

__global__ __launch_bounds__(256) void scan_passC(
    const unsigned short* __restrict__ epsB,
    const unsigned short* __restrict__ xcB,
    const unsigned short* __restrict__ xdbl2B,
    const float* __restrict__ D_skip, const float* __restrict__ S0,
    unsigned short* __restrict__ yB) {
  const int d = blockIdx.x * 256 + threadIdx.x;
  const int b = blockIdx.y, ch = blockIdx.z;
  const size_t bl0 = (size_t)b * LL + (size_t)ch * LC;
  const unsigned short* ep = epsB + bl0 * DSSM + d;
  const unsigned short* up = xcB + bl0 * DSSM + d;
  const unsigned short* kqp = xdbl2B + bl0 * NXD + 512;
  unsigned short* yp = yB + bl0 * DINNER + d;
  const float Dv = D_skip[d];
  const size_t base = (size_t)ch * BDN + (((size_t)b * DSSM + d) << 4);
  float S[16];
#pragma unroll
  for (int n4 = 0; n4 < 4; n4++) {
    const float4 v = ((const float4*)(S0 + base))[n4];
    S[4 * n4 + 0] = v.x; S[4 * n4 + 1] = v.y;
    S[4 * n4 + 2] = v.z; S[4 * n4 + 3] = v.w;
  }
#pragma unroll 2
  for (int j = 0; j < LC; j++) {
    float kv[16], qv[16];
    load_bf16x16(kqp + (size_t)j * NXD, kv);       // uniform
    load_bf16x16(kqp + (size_t)j * NXD + 16, qv);  // uniform
    const float e = bf2f(ep[(size_t)j * DSSM]);
    const float u = bf2f(up[(size_t)j * DSSM]);
    float y0 = 0.f, y1 = 0.f, y2 = 0.f, y3 = 0.f;
#pragma unroll
    for (int n = 0; n < 16; n += 4) {
      const float t00 = e * kv[n + 0], t01 = e * kv[n + 1];
      const float t02 = e * kv[n + 2], t03 = e * kv[n + 3];
      S[n + 0] = fmaf(S[n + 0], fmaf(-t00, kv[n + 0], 1.f), t00 * u);
      S[n + 1] = fmaf(S[n + 1], fmaf(-t01, kv[n + 1], 1.f), t01 * u);
      S[n + 2] = fmaf(S[n + 2], fmaf(-t02, kv[n + 2], 1.f), t02 * u);
      S[n + 3] = fmaf(S[n + 3], fmaf(-t03, kv[n + 3], 1.f), t03 * u);
      y0 = fmaf(S[n + 0], qv[n + 0], y0);
      y1 = fmaf(S[n + 1], qv[n + 1], y1);
      y2 = fmaf(S[n + 2], qv[n + 2], y2);
      y3 = fmaf(S[n + 3], qv[n + 3], y3);
    }
    const float yv = fmaf(Dv, u, (y0 + y1) + (y2 + y3));
    yp[(size_t)j * DINNER] = f2bf(yv);
  }
}

// ---------------------------------------------------------------------------
extern "C" void kernel_launch(void* const* d_in, const int* in_sizes, int n_in,
                              void* d_out, int out_size, void* d_ws, size_t ws_size,
                              hipStream_t stream) {
  const float* hidden  = (const float*)d_in[0];
  const float* W_in    = (const float*)d_in[1];
  const float* cxw     = (const float*)d_in[2];
  const float* cxb     = (const float*)d_in[3];
  const float* czw     = (const float*)d_in[4];
  const float* czb     = (const float*)d_in[5];
  const float* W_xproj = (const float*)d_in[6];
  const float* W_dt    = (const float*)d_in[7];
  const float* b_dt    = (const float*)d_in[8];
  const float* D_skip  = (const float*)d_in[9];
  const float* W_out   = (const float*)d_in[10];
  float* out = (float*)d_out;

  const size_t ML  = (size_t)BB * LL;      // 16384
  const size_t MK5 = ML * DSSM;            // 8.4M
  const size_t MN  = ML * DINNER;          // 16.8M
  const size_t WIN = (size_t)DINNER * DMODEL;
  const size_t WOU = (size_t)DMODEL * DINNER;
  const size_t WCT = (size_t)NXD * DMODEL; // 640*512
  const size_t CB  = (size_t)CCH * BDN;    // 4.19M floats

  // layout (~141 MB): hidB+xzB at the end so Ach/Bch/S0 alias them exactly.
  unsigned short* WinB   = (unsigned short*)d_ws;       // WIN
  unsigned short* WoutB  = WinB + WIN;                  // WOU
  unsigned short* WcatB  = WoutB + WOU;                 // WCT
  unsigned short* xcB    = WcatB + WCT;                 // MK5
  unsigned short* yB     = xcB + MK5;                   // MN
  unsigned short* xdbl2B = yB + MN;                     // ML*NXD
  unsigned short* epsB   = xdbl2B + ML * NXD;           // MK5
  unsigned short* hidB   = epsB + MK5;                  // MK5
  unsigned short* xzB    = hidB + MK5;                  // MN
  float* Ach = (float*)hidB;     // 3*CB floats == hidB+xzB bytes exactly
  float* Bch = Ach + CB;
  float* S0  = Bch + CB;

  // 0) fp32 -> bf16 planes (fused) ; fused weight build
  prep_kernel<<<2304, 256, 0, stream>>>(hidden, W_in, W_out, hidB, WinB, WoutB,
                                        (int)(MK5 / 4), (int)(WIN / 4));
  weff_kernel<<<dim3(2, NXD), 256, 0, stream>>>(W_dt, W_xproj, WcatB);

  // 1) xz = hidden @ W_in^T   (bf16 MFMA; M=16384, N=1024, K=512; bf16 out)
  gemm_bf16<true><<<(16384 / 128) * (1024 / 128), 256, 0, stream>>>(
      hidB, WinB, xzB, DMODEL, DINNER / 128);

  // 2) depthwise conv + SiLU  (bf16 in; xcB + yB z-half bf16)
  conv_silu_kernel<<<dim3(DINNER / 256, LL / CLW, BB), 256, 0, stream>>>(
      xzB, cxw, cxb, czw, czb, xcB, yB);

  // 3) xdbl2 = xc @ Wcat^T  (bf16 MFMA; M=16384, N=640, K=512; bf16 out)
  //    cols 0..511 = dt, 512..527 = k, 528..543 = q
  gemm_bf16<true><<<(16384 / 128) * (NXD / 128), 256, 0, stream>>>(
      xcB, WcatB, xdbl2B, DMODEL, NXD / 128);

  // 4) eps = softplus(dt+b_dt)/(1+delta*k2) -> bf16 (separate thin pass)
  dteps2_kernel<<<dim3((unsigned)ML), 256, 0, stream>>>(xdbl2B, b_dt, epsB);

  // 5) chunked scan -> y into yB channels 0..511
  scan_passA<<<dim3(2, BB, CCH), 256, 0, stream>>>(epsB, xcB, xdbl2B, Ach, Bch);
  scan_passB<<<dim3(BDN / 256), 256, 0, stream>>>(Ach, Bch, S0);
  scan_passC<<<dim3(2, BB, CCH), 256, 0, stream>>>(
      epsB, xcB, xdbl2B, D_skip, S0, yB);

  // 6) out = ycat @ W_out^T  (bf16 MFMA; M=16384, N=512, K=1024; fp32 out)
  gemm_bf16<false><<<(16384 / 128) * (512 / 128), 256, 0, stream>>>(
      yB, WoutB, out, DINNER, DMODEL / 128);
}